// Round 4
// baseline (1488.889 us; speedup 1.0000x reference)
//
#include <hip/hip_runtime.h>
#include <math.h>

// Fast guided filter — two-pass hybrid precision.
// Pass 1 (fp32, fused): staging -> A,b -> 8 directional convs -> argmin ->
//   trunc/clamp -> out. Pixels whose argmin is a near-tie with a large
//   potential flip error (margin < TAU && ad1+ad2 > MAG) are appended to a
//   list in d_ws.
// Pass 2 (fp64, tiny): grid-stride over the list, recompute those pixels with
//   the round-3-validated fp64 math (matches the fp64 "np" reference) and
//   overwrite. Expected ~1-5% of pixels -> a few us.
//
// Error budget: fp32 |delta d| <= ~1.2e-2 worst case; TAU=0.05 covers 4x.
// Non-risky flip error <= ad1+ad2 <= 2.0, plus trunc-boundary +-1 -> <= 3.0,
// under the 5.1 absmax threshold. Risky pixels are bit-matched to ~1e-12.

#define TX 64
#define TY 16
#define SW (TX + 4)   // 68
#define SH (TY + 4)   // 20
#define AW (TX + 2)   // 66
#define AH (TY + 2)   // 18
#define NT 256

#define TAU 0.05f
#define MAG 2.0f

__device__ __forceinline__ float fast_rcp_f32(float v) {
#if __has_builtin(__builtin_amdgcn_rcpf)
    float r = __builtin_amdgcn_rcpf(v);
#else
    float r = 1.0f / v;
#endif
    float e = fmaf(-v, r, 1.0f);   // one Newton step -> ~0.5 ulp
    return fmaf(r, e, r);
}

__device__ __forceinline__ double fast_rcp_f64(double v) {
#if __has_builtin(__builtin_amdgcn_rcp)
    double r = __builtin_amdgcn_rcp(v);
#else
    double r = 1.0 / v;
#endif
    double e = fma(-v, r, 1.0);
    r = fma(r, e, r);
    e = fma(-v, r, 1.0);
    r = fma(r, e, r);
    return r;
}

__global__ __launch_bounds__(NT) void fgf_main_kernel(
    const float* __restrict__ x, const float* __restrict__ y,
    float* __restrict__ out, int* __restrict__ meta, int* __restrict__ list,
    int cap, int H, int W)
{
    __shared__ float sxs[SH][SW];
    __shared__ float sys[SH][SW];
    __shared__ float sA[AH][AW];
    __shared__ float sB[AH][AW];

    const int c   = blockIdx.z;
    const int ox0 = blockIdx.x * TX;
    const int oy0 = blockIdx.y * TY;
    const size_t plane = (size_t)H * (size_t)W;
    const float* xc = x + (size_t)c * plane;
    const float* yc = y + (size_t)c * plane;

    const int tid = threadIdx.y * 64 + threadIdx.x;

    // ---- stage 1: inputs with replicate clamp ----
    for (int i = tid; i < SH * SW; i += NT) {
        int ly = i / SW, lx = i - ly * SW;
        int gy = oy0 - 2 + ly;
        int gx = ox0 - 2 + lx;
        gy = gy < 0 ? 0 : (gy >= H ? H - 1 : gy);
        gx = gx < 0 ? 0 : (gx >= W ? W - 1 : gx);
        size_t gidx = (size_t)gy * W + gx;
        sxs[ly][lx] = xc[gidx];
        sys[ly][lx] = yc[gidx];
    }
    __syncthreads();

    // ---- stage 2: A,b in fp32; zero outside image ----
    const float EPS81 = 81.0f * 1.0e-4f;
    const float INV9  = 1.0f / 9.0f;
    for (int i = tid; i < AH * AW; i += NT) {
        int ly = i / AW, lx = i - ly * AW;
        int ay = oy0 - 1 + ly;
        int ax = ox0 - 1 + lx;
        float Av = 0.0f, Bv = 0.0f;
        if (ay >= 0 && ay < H && ax >= 0 && ax < W) {
            float sx4 = 0.f, sy4 = 0.f, sxy = 0.f, sxx = 0.f;
#pragma unroll
            for (int dy = 0; dy < 3; dy++) {
#pragma unroll
                for (int dx = 0; dx < 3; dx++) {
                    float xv = sxs[ly + dy][lx + dx];
                    float yv = sys[ly + dy][lx + dx];
                    sx4 += xv;
                    sy4 += yv;
                    sxy = fmaf(xv, yv, sxy);
                    sxx = fmaf(xv, xv, sxx);
                }
            }
            float num = fmaf(-sx4, sy4, 9.0f * sxy);
            float den = fmaf(-sx4, sx4, fmaf(9.0f, sxx, EPS81));
            Av = num * fast_rcp_f32(den);
            Bv = fmaf(-Av, sx4, sy4) * INV9;
        }
        sA[ly][lx] = Av;
        sB[ly][lx] = Bv;
    }
    __syncthreads();

    // ---- stage 3: sliding-window directional convs + argmin (fp32) ----
    const float I6 = 1.0f / 6.0f;
    const int tx = threadIdx.x;          // 0..63
    const int r0 = threadIdx.y * 4;      // 4 contiguous rows per thread
    const int xg = ox0 + tx;
    const bool xok = (xg < W);

    float tA[3], mA[3], pA[3], tB[3], mB[3], pB[3];
#pragma unroll
    for (int cc = 0; cc < 3; cc++) {
        float a0 = sA[r0 + 0][tx + cc];
        float a1 = sA[r0 + 1][tx + cc];
        float a2 = sA[r0 + 2][tx + cc];
        tA[cc] = a0 + a1; mA[cc] = a1 + a2; pA[cc] = a2;
        float b0 = sB[r0 + 0][tx + cc];
        float b1 = sB[r0 + 1][tx + cc];
        float b2 = sB[r0 + 2][tx + cc];
        tB[cc] = b0 + b1; mB[cc] = b1 + b2; pB[cc] = b2;
    }

#pragma unroll
    for (int step = 0; step < 4; step++) {
        const int r  = r0 + step;
        const int yg = oy0 + r;
        if (xok && yg < H) {
            float fA0 = tA[0] + pA[0], fA1 = tA[1] + pA[1], fA2 = tA[2] + pA[2];
            float fB0 = tB[0] + pB[0], fB1 = tB[1] + pB[1], fB2 = tB[2] + pB[2];

            float t01A = tA[0] + tA[1], t12A = tA[1] + tA[2];
            float m01A = mA[0] + mA[1], m12A = mA[1] + mA[2];
            float t01B = tB[0] + tB[1], t12B = tB[1] + tB[2];
            float m01B = mB[0] + mB[1], m12B = mB[1] + mB[2];

            // L, R, U, D, NW, NE, SW, SE
            float cA[8], cB[8];
            cA[0] = (fA0 + fA1) * I6;      cB[0] = (fB0 + fB1) * I6;
            cA[1] = (fA1 + fA2) * I6;      cB[1] = (fB1 + fB2) * I6;
            cA[2] = (t01A + tA[2]) * I6;   cB[2] = (t01B + tB[2]) * I6;
            cA[3] = (m01A + mA[2]) * I6;   cB[3] = (m01B + mB[2]) * I6;
            cA[4] = t01A * 0.25f;          cB[4] = t01B * 0.25f;
            cA[5] = t12A * 0.25f;          cB[5] = t12B * 0.25f;
            cA[6] = m01A * 0.25f;          cB[6] = m01B * 0.25f;
            cA[7] = m12A * 0.25f;          cB[7] = m12B * 0.25f;

            float im = sxs[r + 2][tx + 2];

            float best_ad = 1.0e30f, best_d = 0.0f;
            float sec_ad  = 1.0e30f;
#pragma unroll
            for (int k = 0; k < 8; k++) {
                float d  = fmaf(cA[k], im, cB[k]) - im;
                float ad = fabsf(d);
                if (ad < best_ad) {
                    sec_ad = best_ad;
                    best_ad = ad; best_d = d;
                } else if (ad < sec_ad) {
                    sec_ad = ad;
                }
            }

            float res = truncf(best_d + im);
            res = fminf(fmaxf(res, 0.0f), 255.0f);
            size_t oid = (size_t)c * plane + (size_t)yg * W + xg;
            out[oid] = res;

            // near-tie with large potential flip error -> fp64 fixup list
            bool risky = (sec_ad - best_ad < TAU) && (best_ad + sec_ad > MAG);
            if (risky) {
                int slot = atomicAdd(meta, 1);
                if (slot < cap) list[slot] = (int)oid;
            }
        }

        if (step < 3) {
#pragma unroll
            for (int cc = 0; cc < 3; cc++) {
                float nA = sA[r0 + step + 3][tx + cc];
                float nB = sB[r0 + step + 3][tx + cc];
                tA[cc] = mA[cc]; mA[cc] = pA[cc] + nA; pA[cc] = nA;
                tB[cc] = mB[cc]; mB[cc] = pB[cc] + nB; pB[cc] = nB;
            }
        }
    }
}

// fp64 recompute of listed pixels (round-3-validated math).
__global__ __launch_bounds__(256) void fgf_fixup_kernel(
    const float* __restrict__ x, const float* __restrict__ y,
    float* __restrict__ out, const int* __restrict__ meta,
    const int* __restrict__ list, int cap, int H, int W)
{
    int n = meta[0];
    if (n > cap) n = cap;
    const size_t plane = (size_t)H * (size_t)W;
    const int planei = H * W;
    const double EPS81 = 81.0 * 1.0e-4;
    const double INV9  = 1.0 / 9.0;
    const double I6    = 1.0 / 6.0;

    for (int i = blockIdx.x * blockDim.x + threadIdx.x; i < n;
         i += gridDim.x * blockDim.x) {
        int id  = list[i];
        int c   = id / planei;
        int rem = id - c * planei;
        int py  = rem / W;
        int px  = rem - py * W;
        const float* xc = x + (size_t)c * plane;
        const float* yc = y + (size_t)c * plane;

        double A[3][3], B[3][3];
#pragma unroll
        for (int dy = -1; dy <= 1; dy++) {
#pragma unroll
            for (int dx = -1; dx <= 1; dx++) {
                int ay = py + dy, ax = px + dx;
                double Av = 0.0, Bv = 0.0;
                if (ay >= 0 && ay < H && ax >= 0 && ax < W) {
                    double sx4 = 0.0, sy4 = 0.0, sxy = 0.0, sxx = 0.0;
#pragma unroll
                    for (int ky = -1; ky <= 1; ky++) {
#pragma unroll
                        for (int kx = -1; kx <= 1; kx++) {
                            int gy = ay + ky; gy = gy < 0 ? 0 : (gy >= H ? H - 1 : gy);
                            int gx = ax + kx; gx = gx < 0 ? 0 : (gx >= W ? W - 1 : gx);
                            double xv = (double)xc[(size_t)gy * W + gx];
                            double yv = (double)yc[(size_t)gy * W + gx];
                            sx4 += xv; sy4 += yv;
                            sxy = fma(xv, yv, sxy);
                            sxx = fma(xv, xv, sxx);
                        }
                    }
                    double num = fma(-sx4, sy4, 9.0 * sxy);
                    double den = fma(-sx4, sx4, fma(9.0, sxx, EPS81));
                    Av = num * fast_rcp_f64(den);
                    Bv = fma(-Av, sx4, sy4) * INV9;
                }
                A[dy + 1][dx + 1] = Av;
                B[dy + 1][dx + 1] = Bv;
            }
        }

        double at0 = A[0][0] + A[1][0], at1 = A[0][1] + A[1][1], at2 = A[0][2] + A[1][2];
        double am0 = A[1][0] + A[2][0], am1 = A[1][1] + A[2][1], am2 = A[1][2] + A[2][2];
        double ac0 = at0 + A[2][0],     ac1 = at1 + A[2][1],     ac2 = at2 + A[2][2];
        double bt0 = B[0][0] + B[1][0], bt1 = B[0][1] + B[1][1], bt2 = B[0][2] + B[1][2];
        double bm0 = B[1][0] + B[2][0], bm1 = B[1][1] + B[2][1], bm2 = B[1][2] + B[2][2];
        double bc0 = bt0 + B[2][0],     bc1 = bt1 + B[2][1],     bc2 = bt2 + B[2][2];

        double cA[8], cB[8];
        cA[0] = (ac0 + ac1) * I6;        cB[0] = (bc0 + bc1) * I6;
        cA[1] = (ac1 + ac2) * I6;        cB[1] = (bc1 + bc2) * I6;
        cA[2] = (at0 + at1 + at2) * I6;  cB[2] = (bt0 + bt1 + bt2) * I6;
        cA[3] = (am0 + am1 + am2) * I6;  cB[3] = (bm0 + bm1 + bm2) * I6;
        cA[4] = (at0 + at1) * 0.25;      cB[4] = (bt0 + bt1) * 0.25;
        cA[5] = (at1 + at2) * 0.25;      cB[5] = (bt1 + bt2) * 0.25;
        cA[6] = (am0 + am1) * 0.25;      cB[6] = (bm0 + bm1) * 0.25;
        cA[7] = (am1 + am2) * 0.25;      cB[7] = (bm1 + bm2) * 0.25;

        double im = (double)xc[(size_t)py * W + px];

        double best_ad = 1.0e300, best_d = 0.0;
#pragma unroll
        for (int k = 0; k < 8; k++) {
            double d  = fma(cA[k], im, cB[k]) - im;
            double ad = fabs(d);
            if (ad < best_ad) { best_ad = ad; best_d = d; }
        }

        double res = trunc(best_d + im);
        res = fmin(fmax(res, 0.0), 255.0);
        out[(size_t)id] = (float)res;
    }
}

extern "C" void kernel_launch(void* const* d_in, const int* in_sizes, int n_in,
                              void* d_out, int out_size, void* d_ws, size_t ws_size,
                              hipStream_t stream) {
    const float* lr_x = (const float*)d_in[0];
    const float* lr_y = (const float*)d_in[1];
    // d_in[2] (hr_x) is dead in the reference computation.
    float* out = (float*)d_out;

    const int plane = in_sizes[0] / 3;
    const int H = (int)(0.5 + sqrt((double)plane));
    const int W = plane / H;

    int* meta = (int*)d_ws;                       // [0] = risky count
    int* list = (int*)((char*)d_ws + 16);
    int cap = (int)((ws_size > 16 ? ws_size - 16 : 0) / sizeof(int));

    hipMemsetAsync(d_ws, 0, 16, stream);          // zero counter (capture-safe)

    dim3 block(64, 4, 1);
    dim3 grid((W + TX - 1) / TX, (H + TY - 1) / TY, 3);
    fgf_main_kernel<<<grid, block, 0, stream>>>(lr_x, lr_y, out, meta, list,
                                                cap, H, W);
    fgf_fixup_kernel<<<256, 256, 0, stream>>>(lr_x, lr_y, out, meta, list,
                                              cap, H, W);
}

// Round 5
// 823.157 us; speedup vs baseline: 1.8088x; 1.8088x over previous
//
#include <hip/hip_runtime.h>
#include <math.h>

// Fast guided filter — two-pass hybrid precision, ATOMIC-FREE compaction.
// Round-4 failure: per-pixel atomicAdd to one global counter serialized the
// whole kernel (VALUBusy 75%->7%, dur 115->1113 us). Round-5: pass 1 writes a
// per-pixel byte MASK (unconditional coalesced store, no atomics, no return
// dependency); pass 2 scans the mask 4 pixels/uint and recomputes risky
// pixels in fp64 (round-3-validated math, matches the fp64 "np" reference).
//
// Error budget: fp32 |delta d| <= ~1.2e-2; TAU=0.05 covers 4x. Non-risky flip
// error <= ad1+ad2 <= MAG=2.0, plus trunc boundary -> <= 3.0 < 5.1 threshold.

#define TX 64
#define TY 16
#define SW (TX + 4)   // 68
#define SH (TY + 4)   // 20
#define AW (TX + 2)   // 66
#define AH (TY + 2)   // 18
#define NT 256

#define TAU 0.05f
#define MAG 2.0f

__device__ __forceinline__ float fast_rcp_f32(float v) {
#if __has_builtin(__builtin_amdgcn_rcpf)
    float r = __builtin_amdgcn_rcpf(v);
#else
    float r = 1.0f / v;
#endif
    float e = fmaf(-v, r, 1.0f);
    return fmaf(r, e, r);
}

__device__ __forceinline__ double fast_rcp_f64(double v) {
#if __has_builtin(__builtin_amdgcn_rcp)
    double r = __builtin_amdgcn_rcp(v);
#else
    double r = 1.0 / v;
#endif
    double e = fma(-v, r, 1.0);
    r = fma(r, e, r);
    e = fma(-v, r, 1.0);
    r = fma(r, e, r);
    return r;
}

__global__ __launch_bounds__(NT) void fgf_main_kernel(
    const float* __restrict__ x, const float* __restrict__ y,
    float* __restrict__ out, unsigned char* __restrict__ mask, int H, int W)
{
    __shared__ float sxs[SH][SW];
    __shared__ float sys[SH][SW];
    __shared__ float sA[AH][AW];
    __shared__ float sB[AH][AW];

    const int c   = blockIdx.z;
    const int ox0 = blockIdx.x * TX;
    const int oy0 = blockIdx.y * TY;
    const size_t plane = (size_t)H * (size_t)W;
    const float* xc = x + (size_t)c * plane;
    const float* yc = y + (size_t)c * plane;

    const int tid = threadIdx.y * 64 + threadIdx.x;

    // ---- stage 1: inputs with replicate clamp ----
    for (int i = tid; i < SH * SW; i += NT) {
        int ly = i / SW, lx = i - ly * SW;
        int gy = oy0 - 2 + ly;
        int gx = ox0 - 2 + lx;
        gy = gy < 0 ? 0 : (gy >= H ? H - 1 : gy);
        gx = gx < 0 ? 0 : (gx >= W ? W - 1 : gx);
        size_t gidx = (size_t)gy * W + gx;
        sxs[ly][lx] = xc[gidx];
        sys[ly][lx] = yc[gidx];
    }
    __syncthreads();

    // ---- stage 2: A,b in fp32; zero outside image ----
    const float EPS81 = 81.0f * 1.0e-4f;
    const float INV9  = 1.0f / 9.0f;
    for (int i = tid; i < AH * AW; i += NT) {
        int ly = i / AW, lx = i - ly * AW;
        int ay = oy0 - 1 + ly;
        int ax = ox0 - 1 + lx;
        float Av = 0.0f, Bv = 0.0f;
        if (ay >= 0 && ay < H && ax >= 0 && ax < W) {
            float sx4 = 0.f, sy4 = 0.f, sxy = 0.f, sxx = 0.f;
#pragma unroll
            for (int dy = 0; dy < 3; dy++) {
#pragma unroll
                for (int dx = 0; dx < 3; dx++) {
                    float xv = sxs[ly + dy][lx + dx];
                    float yv = sys[ly + dy][lx + dx];
                    sx4 += xv;
                    sy4 += yv;
                    sxy = fmaf(xv, yv, sxy);
                    sxx = fmaf(xv, xv, sxx);
                }
            }
            float num = fmaf(-sx4, sy4, 9.0f * sxy);
            float den = fmaf(-sx4, sx4, fmaf(9.0f, sxx, EPS81));
            Av = num * fast_rcp_f32(den);
            Bv = fmaf(-Av, sx4, sy4) * INV9;
        }
        sA[ly][lx] = Av;
        sB[ly][lx] = Bv;
    }
    __syncthreads();

    // ---- stage 3: sliding-window directional convs + argmin (fp32) ----
    const float I6 = 1.0f / 6.0f;
    const int tx = threadIdx.x;          // 0..63
    const int r0 = threadIdx.y * 4;      // 4 contiguous rows per thread
    const int xg = ox0 + tx;
    const bool xok = (xg < W);

    float tA[3], mA[3], pA[3], tB[3], mB[3], pB[3];
#pragma unroll
    for (int cc = 0; cc < 3; cc++) {
        float a0 = sA[r0 + 0][tx + cc];
        float a1 = sA[r0 + 1][tx + cc];
        float a2 = sA[r0 + 2][tx + cc];
        tA[cc] = a0 + a1; mA[cc] = a1 + a2; pA[cc] = a2;
        float b0 = sB[r0 + 0][tx + cc];
        float b1 = sB[r0 + 1][tx + cc];
        float b2 = sB[r0 + 2][tx + cc];
        tB[cc] = b0 + b1; mB[cc] = b1 + b2; pB[cc] = b2;
    }

#pragma unroll
    for (int step = 0; step < 4; step++) {
        const int r  = r0 + step;
        const int yg = oy0 + r;
        if (xok && yg < H) {
            float fA0 = tA[0] + pA[0], fA1 = tA[1] + pA[1], fA2 = tA[2] + pA[2];
            float fB0 = tB[0] + pB[0], fB1 = tB[1] + pB[1], fB2 = tB[2] + pB[2];

            float t01A = tA[0] + tA[1], t12A = tA[1] + tA[2];
            float m01A = mA[0] + mA[1], m12A = mA[1] + mA[2];
            float t01B = tB[0] + tB[1], t12B = tB[1] + tB[2];
            float m01B = mB[0] + mB[1], m12B = mB[1] + mB[2];

            // L, R, U, D, NW, NE, SW, SE
            float cA[8], cB[8];
            cA[0] = (fA0 + fA1) * I6;      cB[0] = (fB0 + fB1) * I6;
            cA[1] = (fA1 + fA2) * I6;      cB[1] = (fB1 + fB2) * I6;
            cA[2] = (t01A + tA[2]) * I6;   cB[2] = (t01B + tB[2]) * I6;
            cA[3] = (m01A + mA[2]) * I6;   cB[3] = (m01B + mB[2]) * I6;
            cA[4] = t01A * 0.25f;          cB[4] = t01B * 0.25f;
            cA[5] = t12A * 0.25f;          cB[5] = t12B * 0.25f;
            cA[6] = m01A * 0.25f;          cB[6] = m01B * 0.25f;
            cA[7] = m12A * 0.25f;          cB[7] = m12B * 0.25f;

            float im = sxs[r + 2][tx + 2];

            float best_ad = 1.0e30f, best_d = 0.0f;
            float sec_ad  = 1.0e30f;
#pragma unroll
            for (int k = 0; k < 8; k++) {
                float d  = fmaf(cA[k], im, cB[k]) - im;
                float ad = fabsf(d);
                if (ad < best_ad) {
                    sec_ad = best_ad;
                    best_ad = ad; best_d = d;
                } else if (ad < sec_ad) {
                    sec_ad = ad;
                }
            }

            float res = truncf(best_d + im);
            res = fminf(fmaxf(res, 0.0f), 255.0f);
            size_t oid = (size_t)c * plane + (size_t)yg * W + xg;
            out[oid] = res;

            // near-tie with large potential flip error -> fp64 fixup.
            // Unconditional coalesced byte store; NO atomics (round-4 lesson).
            bool risky = (sec_ad - best_ad < TAU) && (best_ad + sec_ad > MAG);
            mask[oid] = risky ? 1 : 0;
        }

        if (step < 3) {
#pragma unroll
            for (int cc = 0; cc < 3; cc++) {
                float nA = sA[r0 + step + 3][tx + cc];
                float nB = sB[r0 + step + 3][tx + cc];
                tA[cc] = mA[cc]; mA[cc] = pA[cc] + nA; pA[cc] = nA;
                tB[cc] = mB[cc]; mB[cc] = pB[cc] + nB; pB[cc] = nB;
            }
        }
    }
}

// fp64 recompute of one pixel (round-3-validated math).
__device__ void fixup_pixel(const float* __restrict__ x,
                            const float* __restrict__ y,
                            float* __restrict__ out,
                            int id, int H, int W)
{
    const size_t plane = (size_t)H * (size_t)W;
    const int planei = H * W;
    const double EPS81 = 81.0 * 1.0e-4;
    const double INV9  = 1.0 / 9.0;
    const double I6    = 1.0 / 6.0;

    int c   = id / planei;
    int rem = id - c * planei;
    int py  = rem / W;
    int px  = rem - py * W;
    const float* xc = x + (size_t)c * plane;
    const float* yc = y + (size_t)c * plane;

    double A[3][3], B[3][3];
#pragma unroll
    for (int dy = -1; dy <= 1; dy++) {
#pragma unroll
        for (int dx = -1; dx <= 1; dx++) {
            int ay = py + dy, ax = px + dx;
            double Av = 0.0, Bv = 0.0;
            if (ay >= 0 && ay < H && ax >= 0 && ax < W) {
                double sx4 = 0.0, sy4 = 0.0, sxy = 0.0, sxx = 0.0;
#pragma unroll
                for (int ky = -1; ky <= 1; ky++) {
#pragma unroll
                    for (int kx = -1; kx <= 1; kx++) {
                        int gy = ay + ky; gy = gy < 0 ? 0 : (gy >= H ? H - 1 : gy);
                        int gx = ax + kx; gx = gx < 0 ? 0 : (gx >= W ? W - 1 : gx);
                        double xv = (double)xc[(size_t)gy * W + gx];
                        double yv = (double)yc[(size_t)gy * W + gx];
                        sx4 += xv; sy4 += yv;
                        sxy = fma(xv, yv, sxy);
                        sxx = fma(xv, xv, sxx);
                    }
                }
                double num = fma(-sx4, sy4, 9.0 * sxy);
                double den = fma(-sx4, sx4, fma(9.0, sxx, EPS81));
                Av = num * fast_rcp_f64(den);
                Bv = fma(-Av, sx4, sy4) * INV9;
            }
            A[dy + 1][dx + 1] = Av;
            B[dy + 1][dx + 1] = Bv;
        }
    }

    double at0 = A[0][0] + A[1][0], at1 = A[0][1] + A[1][1], at2 = A[0][2] + A[1][2];
    double am0 = A[1][0] + A[2][0], am1 = A[1][1] + A[2][1], am2 = A[1][2] + A[2][2];
    double ac0 = at0 + A[2][0],     ac1 = at1 + A[2][1],     ac2 = at2 + A[2][2];
    double bt0 = B[0][0] + B[1][0], bt1 = B[0][1] + B[1][1], bt2 = B[0][2] + B[1][2];
    double bm0 = B[1][0] + B[2][0], bm1 = B[1][1] + B[2][1], bm2 = B[1][2] + B[2][2];
    double bc0 = bt0 + B[2][0],     bc1 = bt1 + B[2][1],     bc2 = bt2 + B[2][2];

    double cA[8], cB[8];
    cA[0] = (ac0 + ac1) * I6;        cB[0] = (bc0 + bc1) * I6;
    cA[1] = (ac1 + ac2) * I6;        cB[1] = (bc1 + bc2) * I6;
    cA[2] = (at0 + at1 + at2) * I6;  cB[2] = (bt0 + bt1 + bt2) * I6;
    cA[3] = (am0 + am1 + am2) * I6;  cB[3] = (bm0 + bm1 + bm2) * I6;
    cA[4] = (at0 + at1) * 0.25;      cB[4] = (bt0 + bt1) * 0.25;
    cA[5] = (at1 + at2) * 0.25;      cB[5] = (bt1 + bt2) * 0.25;
    cA[6] = (am0 + am1) * 0.25;      cB[6] = (bm0 + bm1) * 0.25;
    cA[7] = (am1 + am2) * 0.25;      cB[7] = (bm1 + bm2) * 0.25;

    double im = (double)xc[(size_t)py * W + px];

    double best_ad = 1.0e300, best_d = 0.0;
#pragma unroll
    for (int k = 0; k < 8; k++) {
        double d  = fma(cA[k], im, cB[k]) - im;
        double ad = fabs(d);
        if (ad < best_ad) { best_ad = ad; best_d = d; }
    }

    double res = trunc(best_d + im);
    res = fmin(fmax(res, 0.0), 255.0);
    out[(size_t)id] = (float)res;
}

// Scan mask 4 pixels per uint word; recompute risky pixels in fp64.
__global__ __launch_bounds__(256) void fgf_fixup_kernel(
    const float* __restrict__ x, const float* __restrict__ y,
    float* __restrict__ out, const unsigned int* __restrict__ maskw,
    int nwords, int H, int W)
{
    for (int w = blockIdx.x * blockDim.x + threadIdx.x; w < nwords;
         w += gridDim.x * blockDim.x) {
        unsigned int m = maskw[w];
        if (m == 0u) continue;
#pragma unroll
        for (int b = 0; b < 4; b++) {
            if ((m >> (8 * b)) & 0xFFu) {
                fixup_pixel(x, y, out, w * 4 + b, H, W);
            }
        }
    }
}

extern "C" void kernel_launch(void* const* d_in, const int* in_sizes, int n_in,
                              void* d_out, int out_size, void* d_ws, size_t ws_size,
                              hipStream_t stream) {
    const float* lr_x = (const float*)d_in[0];
    const float* lr_y = (const float*)d_in[1];
    // d_in[2] (hr_x) is dead in the reference computation.
    float* out = (float*)d_out;

    const int plane = in_sizes[0] / 3;
    const int H = (int)(0.5 + sqrt((double)plane));
    const int W = plane / H;
    const int total = 3 * plane;          // divisible by 4 (H,W pow2)

    unsigned char* mask = (unsigned char*)d_ws;   // total bytes; every in-range
                                                  // pixel written by pass 1

    dim3 block(64, 4, 1);
    dim3 grid((W + TX - 1) / TX, (H + TY - 1) / TY, 3);
    fgf_main_kernel<<<grid, block, 0, stream>>>(lr_x, lr_y, out, mask, H, W);

    const int nwords = total / 4;
    fgf_fixup_kernel<<<1024, 256, 0, stream>>>(lr_x, lr_y, out,
                                               (const unsigned int*)mask,
                                               nwords, H, W);
}

// Round 6
// 391.313 us; speedup vs baseline: 3.8049x; 2.1036x over previous
//
#include <hip/hip_runtime.h>
#include <math.h>

// Fast guided filter — two-pass hybrid precision, ballot-bitmask compaction.
// Round-5 lesson: byte-mask + loose risky predicate (margin<0.05 && ad1+ad2>2)
// flagged 8.2% of pixels -> 515 us fp64 fixup. Round-6:
//  1. EXACT flip-error criterion: risky iff some k!=best has
//     ad_k < best_ad + TAU && |d_k - d_best| > 4.0  (flip error <= |dk-db|+1
//     trunc + ~0.01 fp32 noise < 5.1 threshold). Same-sign ties are harmless.
//  2. Wave ballot -> 1 u64 per 64-pixel row (mask traffic 25 MB -> 3 MB).
// Fixup recomputes flagged pixels with round-3-validated fp64 math.

#define TX 64
#define TY 16
#define SW (TX + 4)   // 68
#define SH (TY + 4)   // 20
#define AW (TX + 2)   // 66
#define AH (TY + 2)   // 18
#define NT 256

#define TAU  0.05f    // fp32 |delta d| <= ~1.2e-2 worst case; 4x cover
#define DMAX 4.0f     // max tolerated |d_k - d_best| for an unflagged tie

__device__ __forceinline__ float fast_rcp_f32(float v) {
#if __has_builtin(__builtin_amdgcn_rcpf)
    float r = __builtin_amdgcn_rcpf(v);
#else
    float r = 1.0f / v;
#endif
    float e = fmaf(-v, r, 1.0f);
    return fmaf(r, e, r);
}

__device__ __forceinline__ double fast_rcp_f64(double v) {
#if __has_builtin(__builtin_amdgcn_rcp)
    double r = __builtin_amdgcn_rcp(v);
#else
    double r = 1.0 / v;
#endif
    double e = fma(-v, r, 1.0);
    r = fma(r, e, r);
    e = fma(-v, r, 1.0);
    r = fma(r, e, r);
    return r;
}

__global__ __launch_bounds__(NT) void fgf_main_kernel(
    const float* __restrict__ x, const float* __restrict__ y,
    float* __restrict__ out, unsigned long long* __restrict__ maskw,
    int wpr, int H, int W)
{
    __shared__ float sxs[SH][SW];
    __shared__ float sys[SH][SW];
    __shared__ float sA[AH][AW];
    __shared__ float sB[AH][AW];

    const int c   = blockIdx.z;
    const int ox0 = blockIdx.x * TX;
    const int oy0 = blockIdx.y * TY;
    const size_t plane = (size_t)H * (size_t)W;
    const float* xc = x + (size_t)c * plane;
    const float* yc = y + (size_t)c * plane;

    const int tid = threadIdx.y * 64 + threadIdx.x;

    // ---- stage 1: inputs with replicate clamp ----
    for (int i = tid; i < SH * SW; i += NT) {
        int ly = i / SW, lx = i - ly * SW;
        int gy = oy0 - 2 + ly;
        int gx = ox0 - 2 + lx;
        gy = gy < 0 ? 0 : (gy >= H ? H - 1 : gy);
        gx = gx < 0 ? 0 : (gx >= W ? W - 1 : gx);
        size_t gidx = (size_t)gy * W + gx;
        sxs[ly][lx] = xc[gidx];
        sys[ly][lx] = yc[gidx];
    }
    __syncthreads();

    // ---- stage 2: A,b in fp32; zero outside image ----
    const float EPS81 = 81.0f * 1.0e-4f;
    const float INV9  = 1.0f / 9.0f;
    for (int i = tid; i < AH * AW; i += NT) {
        int ly = i / AW, lx = i - ly * AW;
        int ay = oy0 - 1 + ly;
        int ax = ox0 - 1 + lx;
        float Av = 0.0f, Bv = 0.0f;
        if (ay >= 0 && ay < H && ax >= 0 && ax < W) {
            float sx4 = 0.f, sy4 = 0.f, sxy = 0.f, sxx = 0.f;
#pragma unroll
            for (int dy = 0; dy < 3; dy++) {
#pragma unroll
                for (int dx = 0; dx < 3; dx++) {
                    float xv = sxs[ly + dy][lx + dx];
                    float yv = sys[ly + dy][lx + dx];
                    sx4 += xv;
                    sy4 += yv;
                    sxy = fmaf(xv, yv, sxy);
                    sxx = fmaf(xv, xv, sxx);
                }
            }
            float num = fmaf(-sx4, sy4, 9.0f * sxy);
            float den = fmaf(-sx4, sx4, fmaf(9.0f, sxx, EPS81));
            Av = num * fast_rcp_f32(den);
            Bv = fmaf(-Av, sx4, sy4) * INV9;
        }
        sA[ly][lx] = Av;
        sB[ly][lx] = Bv;
    }
    __syncthreads();

    // ---- stage 3: sliding-window directional convs + argmin (fp32) ----
    const float I6 = 1.0f / 6.0f;
    const int tx = threadIdx.x;          // 0..63 — one wave per output row
    const int r0 = threadIdx.y * 4;      // 4 contiguous rows per thread
    const int xg = ox0 + tx;
    const bool xok = (xg < W);

    float tA[3], mA[3], pA[3], tB[3], mB[3], pB[3];
#pragma unroll
    for (int cc = 0; cc < 3; cc++) {
        float a0 = sA[r0 + 0][tx + cc];
        float a1 = sA[r0 + 1][tx + cc];
        float a2 = sA[r0 + 2][tx + cc];
        tA[cc] = a0 + a1; mA[cc] = a1 + a2; pA[cc] = a2;
        float b0 = sB[r0 + 0][tx + cc];
        float b1 = sB[r0 + 1][tx + cc];
        float b2 = sB[r0 + 2][tx + cc];
        tB[cc] = b0 + b1; mB[cc] = b1 + b2; pB[cc] = b2;
    }

#pragma unroll
    for (int step = 0; step < 4; step++) {
        const int r  = r0 + step;
        const int yg = oy0 + r;
        bool risky = false;
        if (xok && yg < H) {
            float fA0 = tA[0] + pA[0], fA1 = tA[1] + pA[1], fA2 = tA[2] + pA[2];
            float fB0 = tB[0] + pB[0], fB1 = tB[1] + pB[1], fB2 = tB[2] + pB[2];

            float t01A = tA[0] + tA[1], t12A = tA[1] + tA[2];
            float m01A = mA[0] + mA[1], m12A = mA[1] + mA[2];
            float t01B = tB[0] + tB[1], t12B = tB[1] + tB[2];
            float m01B = mB[0] + mB[1], m12B = mB[1] + mB[2];

            // L, R, U, D, NW, NE, SW, SE
            float cA[8], cB[8];
            cA[0] = (fA0 + fA1) * I6;      cB[0] = (fB0 + fB1) * I6;
            cA[1] = (fA1 + fA2) * I6;      cB[1] = (fB1 + fB2) * I6;
            cA[2] = (t01A + tA[2]) * I6;   cB[2] = (t01B + tB[2]) * I6;
            cA[3] = (m01A + mA[2]) * I6;   cB[3] = (m01B + mB[2]) * I6;
            cA[4] = t01A * 0.25f;          cB[4] = t01B * 0.25f;
            cA[5] = t12A * 0.25f;          cB[5] = t12B * 0.25f;
            cA[6] = m01A * 0.25f;          cB[6] = m01B * 0.25f;
            cA[7] = m12A * 0.25f;          cB[7] = m12B * 0.25f;

            float im = sxs[r + 2][tx + 2];

            float dv[8], av[8];
            float best_ad = 1.0e30f, best_d = 0.0f;
#pragma unroll
            for (int k = 0; k < 8; k++) {
                float d  = fmaf(cA[k], im, cB[k]) - im;
                float ad = fabsf(d);
                dv[k] = d; av[k] = ad;
                if (ad < best_ad) { best_ad = ad; best_d = d; }
            }

            // exact flip-error test: a tie only matters if choosing the other
            // candidate moves the output by > DMAX.
            float lim = best_ad + TAU;
#pragma unroll
            for (int k = 0; k < 8; k++) {
                risky = risky | ((av[k] < lim) & (fabsf(dv[k] - best_d) > DMAX));
            }

            float res = truncf(best_d + im);
            res = fminf(fmaxf(res, 0.0f), 255.0f);
            out[(size_t)c * plane + (size_t)yg * W + xg] = res;
        }

        // wave == one 64-pixel row: one u64 bitmask store by lane 0
        unsigned long long bal = __ballot(risky);
        if (tx == 0 && yg < H) {
            maskw[((size_t)c * H + yg) * wpr + blockIdx.x] = bal;
        }

        if (step < 3) {
#pragma unroll
            for (int cc = 0; cc < 3; cc++) {
                float nA = sA[r0 + step + 3][tx + cc];
                float nB = sB[r0 + step + 3][tx + cc];
                tA[cc] = mA[cc]; mA[cc] = pA[cc] + nA; pA[cc] = nA;
                tB[cc] = mB[cc]; mB[cc] = pB[cc] + nB; pB[cc] = nB;
            }
        }
    }
}

// fp64 recompute of one pixel (round-3-validated math).
__device__ void fixup_pixel(const float* __restrict__ x,
                            const float* __restrict__ y,
                            float* __restrict__ out,
                            int c, int py, int px, int H, int W)
{
    const size_t plane = (size_t)H * (size_t)W;
    const double EPS81 = 81.0 * 1.0e-4;
    const double INV9  = 1.0 / 9.0;
    const double I6    = 1.0 / 6.0;

    const float* xc = x + (size_t)c * plane;
    const float* yc = y + (size_t)c * plane;

    double A[3][3], B[3][3];
#pragma unroll
    for (int dy = -1; dy <= 1; dy++) {
#pragma unroll
        for (int dx = -1; dx <= 1; dx++) {
            int ay = py + dy, ax = px + dx;
            double Av = 0.0, Bv = 0.0;
            if (ay >= 0 && ay < H && ax >= 0 && ax < W) {
                double sx4 = 0.0, sy4 = 0.0, sxy = 0.0, sxx = 0.0;
#pragma unroll
                for (int ky = -1; ky <= 1; ky++) {
#pragma unroll
                    for (int kx = -1; kx <= 1; kx++) {
                        int gy = ay + ky; gy = gy < 0 ? 0 : (gy >= H ? H - 1 : gy);
                        int gx = ax + kx; gx = gx < 0 ? 0 : (gx >= W ? W - 1 : gx);
                        double xv = (double)xc[(size_t)gy * W + gx];
                        double yv = (double)yc[(size_t)gy * W + gx];
                        sx4 += xv; sy4 += yv;
                        sxy = fma(xv, yv, sxy);
                        sxx = fma(xv, xv, sxx);
                    }
                }
                double num = fma(-sx4, sy4, 9.0 * sxy);
                double den = fma(-sx4, sx4, fma(9.0, sxx, EPS81));
                Av = num * fast_rcp_f64(den);
                Bv = fma(-Av, sx4, sy4) * INV9;
            }
            A[dy + 1][dx + 1] = Av;
            B[dy + 1][dx + 1] = Bv;
        }
    }

    double at0 = A[0][0] + A[1][0], at1 = A[0][1] + A[1][1], at2 = A[0][2] + A[1][2];
    double am0 = A[1][0] + A[2][0], am1 = A[1][1] + A[2][1], am2 = A[1][2] + A[2][2];
    double ac0 = at0 + A[2][0],     ac1 = at1 + A[2][1],     ac2 = at2 + A[2][2];
    double bt0 = B[0][0] + B[1][0], bt1 = B[0][1] + B[1][1], bt2 = B[0][2] + B[1][2];
    double bm0 = B[1][0] + B[2][0], bm1 = B[1][1] + B[2][1], bm2 = B[1][2] + B[2][2];
    double bc0 = bt0 + B[2][0],     bc1 = bt1 + B[2][1],     bc2 = bt2 + B[2][2];

    double cA[8], cB[8];
    cA[0] = (ac0 + ac1) * I6;        cB[0] = (bc0 + bc1) * I6;
    cA[1] = (ac1 + ac2) * I6;        cB[1] = (bc1 + bc2) * I6;
    cA[2] = (at0 + at1 + at2) * I6;  cB[2] = (bt0 + bt1 + bt2) * I6;
    cA[3] = (am0 + am1 + am2) * I6;  cB[3] = (bm0 + bm1 + bm2) * I6;
    cA[4] = (at0 + at1) * 0.25;      cB[4] = (bt0 + bt1) * 0.25;
    cA[5] = (at1 + at2) * 0.25;      cB[5] = (bt1 + bt2) * 0.25;
    cA[6] = (am0 + am1) * 0.25;      cB[6] = (bm0 + bm1) * 0.25;
    cA[7] = (am1 + am2) * 0.25;      cB[7] = (bm1 + bm2) * 0.25;

    double im = (double)xc[(size_t)py * W + px];

    double best_ad = 1.0e300, best_d = 0.0;
#pragma unroll
    for (int k = 0; k < 8; k++) {
        double d  = fma(cA[k], im, cB[k]) - im;
        double ad = fabs(d);
        if (ad < best_ad) { best_ad = ad; best_d = d; }
    }

    double res = trunc(best_d + im);
    res = fmin(fmax(res, 0.0), 255.0);
    out[(size_t)c * plane + (size_t)py * W + px] = (float)res;
}

// Scan u64 bitmask (1 bit per pixel); recompute flagged pixels in fp64.
__global__ __launch_bounds__(256) void fgf_fixup_kernel(
    const float* __restrict__ x, const float* __restrict__ y,
    float* __restrict__ out, const unsigned long long* __restrict__ maskw,
    int nwords, int wpr, int H, int W)
{
    const int rows_per_chan = H * wpr;
    for (int w = blockIdx.x * blockDim.x + threadIdx.x; w < nwords;
         w += gridDim.x * blockDim.x) {
        unsigned long long m = maskw[w];
        if (m == 0ull) continue;
        int c   = w / rows_per_chan;
        int rem = w - c * rows_per_chan;
        int py  = rem / wpr;
        int xb  = (rem - py * wpr) * 64;
        while (m) {
            int b = __builtin_ctzll(m);
            m &= m - 1;
            int px = xb + b;
            if (px < W) fixup_pixel(x, y, out, c, py, px, H, W);
        }
    }
}

extern "C" void kernel_launch(void* const* d_in, const int* in_sizes, int n_in,
                              void* d_out, int out_size, void* d_ws, size_t ws_size,
                              hipStream_t stream) {
    const float* lr_x = (const float*)d_in[0];
    const float* lr_y = (const float*)d_in[1];
    // d_in[2] (hr_x) is dead in the reference computation.
    float* out = (float*)d_out;

    const int plane = in_sizes[0] / 3;
    const int H = (int)(0.5 + sqrt((double)plane));
    const int W = plane / H;
    const int wpr = (W + 63) / 64;        // u64 words per row

    unsigned long long* maskw = (unsigned long long*)d_ws;
    // every in-range word is written unconditionally by pass 1 -> no memset

    dim3 block(64, 4, 1);
    dim3 grid((W + TX - 1) / TX, (H + TY - 1) / TY, 3);
    fgf_main_kernel<<<grid, block, 0, stream>>>(lr_x, lr_y, out, maskw,
                                                wpr, H, W);

    const int nwords = 3 * H * wpr;
    fgf_fixup_kernel<<<1024, 256, 0, stream>>>(lr_x, lr_y, out, maskw,
                                               nwords, wpr, H, W);
}